// Round 1
// baseline (154.510 us; speedup 1.0000x reference)
//
#include <hip/hip_runtime.h>
#include <math.h>

#define NPIX 4096
#define NB   4096

// ---- workspace layout (float offsets) ----
#define WQEo   0
#define WKEo   64
#define MISCo  128            // [0]=abias [1]=dbias
#define BVGo   192
#define WVGo   256            // 4096
#define Ao     4352           // B*4096
#define Do     (Ao+16384)
#define VGo    (Do+16384)     // B*4096*64
#define ASo    (VGo+1048576)
#define EASo   (ASo+16384)
#define PERMo  (EASo+16384)   // int
#define BSTo   (PERMo+16384)  // int, B*4096
#define T1o    (BSTo+16384)   // B*4097*64
#define T2o    (T1o+1048832)
#define T3o    (T2o+1048832)
#define SA2o   (T3o+1048832)  // B*4097
#define SB2o   (SA2o+16388)
#define P1o    (SB2o+16388)   // B*64*64
#define P2o    (P1o+16384)
#define P3o    (P2o+16384)
#define PSo    (P3o+16384)    // B*64*2
// total = PSo + 512 = 4380168 floats (~17.5 MB)

__device__ __forceinline__ int bucket_of(float v) {
    int k = (int)((v + 16.0f) * 128.0f);
    k = k < 0 ? 0 : k;
    k = k > (NB - 1) ? (NB - 1) : k;
    return k;
}

// K1: wq_eff = wcq@Wq, wk_eff = wck@Wk, abias/dbias, Wvg = Wg@Wv, bvg = Wg@bv
__global__ void k_prep(const float* __restrict__ Wq, const float* __restrict__ bq,
                       const float* __restrict__ Wk, const float* __restrict__ bk,
                       const float* __restrict__ wcq, const float* __restrict__ wck,
                       const float* __restrict__ Wv, const float* __restrict__ bv,
                       const float* __restrict__ Wg, float* __restrict__ ws) {
    int tid = threadIdx.x;
    if (tid < 64) {
        float s1 = 0.f, s2 = 0.f;
        for (int o = 0; o < 16; o++) { s1 += wcq[o] * Wq[o * 64 + tid]; s2 += wck[o] * Wk[o * 64 + tid]; }
        ws[WQEo + tid] = s1; ws[WKEo + tid] = s2;
        float s3 = 0.f;
        for (int m = 0; m < 64; m++) s3 += Wg[tid * 64 + m] * bv[m];
        ws[BVGo + tid] = s3;
    } else if (tid == 64) {
        float s = 0.f; for (int o = 0; o < 16; o++) s += wcq[o] * bq[o];
        ws[MISCo + 0] = s;
    } else if (tid == 65) {
        float s = 0.f; for (int o = 0; o < 16; o++) s += wck[o] * bk[o];
        ws[MISCo + 1] = s;
    }
    for (int idx = tid; idx < 4096; idx += 256) {
        int o = idx >> 6, c = idx & 63;
        float s = 0.f;
        for (int m = 0; m < 64; m++) s += Wg[o * 64 + m] * Wv[m * 64 + c];
        ws[WVGo + idx] = s;
    }
}

// K2: per-pixel a, d, and vg = Wvg@x + bvg   (x is [B][64][4096])
__global__ void k_proj(const float* __restrict__ x, float* __restrict__ ws) {
    __shared__ float xt[64][68];
    __shared__ float wt[64][68];   // wt[c][o] = Wvg[o][c]
    int b = blockIdx.y, n0 = blockIdx.x * 64, tid = threadIdx.x;
    const float* xb = x + (size_t)b * 64 * 4096;
    for (int idx = tid; idx < 4096; idx += 256) {
        int c = idx >> 6, nl = idx & 63;
        xt[c][nl] = xb[(size_t)c * 4096 + n0 + nl];
        wt[idx & 63][idx >> 6] = ws[WVGo + idx];
    }
    __syncthreads();
    if (tid < 64) {
        float s1 = ws[MISCo + 0], s2 = ws[MISCo + 1];
        for (int c = 0; c < 64; c++) {
            float xv = xt[c][tid];
            s1 += ws[WQEo + c] * xv;
            s2 += ws[WKEo + c] * xv;
        }
        ws[Ao + b * 4096 + n0 + tid] = s1;
        ws[Do + b * 4096 + n0 + tid] = s2;
    }
    int o = tid & 63, nl0 = (tid >> 6) * 16;
    float acc[16];
    float bo = ws[BVGo + o];
#pragma unroll
    for (int k = 0; k < 16; k++) acc[k] = bo;
    for (int c = 0; c < 64; c++) {
        float wv = wt[c][o];
        const float* xr = &xt[c][nl0];
#pragma unroll
        for (int k = 0; k < 16; k++) acc[k] += wv * xr[k];
    }
#pragma unroll
    for (int k = 0; k < 16; k++)
        ws[VGo + ((size_t)(b * 4096) + n0 + nl0 + k) * 64 + o] = acc[k];
}

// K3: per-batch bucket quasi-sort of a: hist -> scan -> scatter (rank by bucket)
__global__ void k_rank(float* __restrict__ ws) {
    __shared__ unsigned int hist[NB];
    __shared__ unsigned int cnt[NB];
    __shared__ unsigned int scanbuf[256];
    int b = blockIdx.x, tid = threadIdx.x;
    const float* Ab = ws + Ao + b * 4096;
    int* perm = (int*)ws + PERMo;
    int* bst  = (int*)ws + BSTo;
    for (int i = tid; i < NB; i += 256) { hist[i] = 0u; cnt[i] = 0u; }
    __syncthreads();
    for (int i = tid; i < 4096; i += 256) atomicAdd(&hist[bucket_of(Ab[i])], 1u);
    __syncthreads();
    unsigned int s = 0u;
    int base = tid * 16;
    for (int k = 0; k < 16; k++) s += hist[base + k];
    scanbuf[tid] = s;
    __syncthreads();
    for (int off = 1; off < 256; off <<= 1) {
        unsigned int v = scanbuf[tid];
        unsigned int u = (tid >= off) ? scanbuf[tid - off] : 0u;
        __syncthreads();
        scanbuf[tid] = v + u;
        __syncthreads();
    }
    unsigned int run = (tid > 0) ? scanbuf[tid - 1] : 0u;
    for (int k = 0; k < 16; k++) {
        unsigned int h = hist[base + k];
        hist[base + k] = run;
        bst[b * NB + base + k] = (int)run;
        run += h;
    }
    __syncthreads();
    for (int i = tid; i < 4096; i += 256) {
        float av = Ab[i];
        int kb = bucket_of(av);
        unsigned int r = hist[kb] + atomicAdd(&cnt[kb], 1u);
        ws[ASo  + b * 4096 + r] = av;
        ws[EASo + b * 4096 + r] = expf(av);
        perm[b * 4096 + r] = i;
    }
}

// K5a: per-chunk partial sums (chunk = 64 sorted positions), lane = channel
__global__ void k_part(float* __restrict__ ws) {
    int b = blockIdx.y, ch = blockIdx.x, lane = threadIdx.x;
    const int* perm = (const int*)ws + PERMo;
    int r0 = ch * 64;
    float s1 = 0.f, s2 = 0.f, s3 = 0.f, sea = 0.f, sa = 0.f;
    for (int k = 0; k < 64; k++) {
        int r = r0 + k;
        int p = perm[b * 4096 + r];
        float av = ws[ASo + b * 4096 + r];
        float ea = ws[EASo + b * 4096 + r];
        float w  = ws[VGo + ((size_t)(b * 4096) + p) * 64 + lane];
        s1 += w; s2 += w * ea; s3 += w * av; sea += ea; sa += av;
    }
    int idx = (b * 64 + ch) * 64 + lane;
    ws[P1o + idx] = s1; ws[P2o + idx] = s2; ws[P3o + idx] = s3;
    if (lane == 0) {
        ws[PSo + (b * 64 + ch) * 2 + 0] = sea;
        ws[PSo + (b * 64 + ch) * 2 + 1] = sa;
    }
}

// K5b: scan chunk partials (exclusive, in place)
__global__ void k_scanpart(float* __restrict__ ws) {
    int tid = threadIdx.x;
    if (tid < 256) {
        int b = tid >> 6, c = tid & 63;
        float r1 = 0.f, r2 = 0.f, r3 = 0.f;
        for (int ch = 0; ch < 64; ch++) {
            int idx = (b * 64 + ch) * 64 + c;
            float t1 = ws[P1o + idx], t2 = ws[P2o + idx], t3 = ws[P3o + idx];
            ws[P1o + idx] = r1; ws[P2o + idx] = r2; ws[P3o + idx] = r3;
            r1 += t1; r2 += t2; r3 += t3;
        }
    } else if (tid < 264) {
        int q = tid - 256; int b = q >> 1, which = q & 1;
        float r = 0.f;
        for (int ch = 0; ch < 64; ch++) {
            int idx = (b * 64 + ch) * 2 + which;
            float t = ws[PSo + idx];
            ws[PSo + idx] = r; r += t;
        }
    }
}

// K5c: write exclusive-prefix tables T1/T2/T3 [b][t][c] and scalar SA2/SB2 [b][t]
__global__ void k_final(float* __restrict__ ws) {
    int b = blockIdx.y, ch = blockIdx.x, lane = threadIdx.x;
    const int* perm = (const int*)ws + PERMo;
    int r0 = ch * 64;
    int idx = (b * 64 + ch) * 64 + lane;
    float r1 = ws[P1o + idx], r2 = ws[P2o + idx], r3 = ws[P3o + idx];
    float rea = ws[PSo + (b * 64 + ch) * 2 + 0];
    float ra  = ws[PSo + (b * 64 + ch) * 2 + 1];
    size_t tb = (size_t)b * 4097 * 64;
    for (int k = 0; k < 64; k++) {
        int r = r0 + k;
        int p = perm[b * 4096 + r];
        float av = ws[ASo + b * 4096 + r];
        float ea = ws[EASo + b * 4096 + r];
        float w  = ws[VGo + ((size_t)(b * 4096) + p) * 64 + lane];
        size_t row = tb + (size_t)r * 64 + lane;
        ws[T1o + row] = r1; ws[T2o + row] = r2; ws[T3o + row] = r3;
        if (lane == 0) { ws[SA2o + b * 4097 + r] = rea; ws[SB2o + b * 4097 + r] = ra; }
        r1 += w; r2 += w * ea; r3 += w * av; rea += ea; ra += av;
    }
    if (ch == 63) {
        size_t row = tb + (size_t)4096 * 64 + lane;
        ws[T1o + row] = r1; ws[T2o + row] = r2; ws[T3o + row] = r3;
        if (lane == 0) { ws[SA2o + b * 4097 + 4096] = rea; ws[SB2o + b * 4097 + 4096] = ra; }
    }
}

// K6: per j: t_j lookup, denom, gather table rows -> LDS transpose -> coalesced out
__global__ void k_out(float* __restrict__ ws, float* __restrict__ out,
                      const float* __restrict__ bg) {
    __shared__ float L1s[64][65], L2s[64][65], L3s[64][65];
    __shared__ float djs[64], edjs[64], invden[64];
    __shared__ int   tarr[64];
    __shared__ float tot1[64], tot3[64], bgs[64];
    int b = blockIdx.y, j0 = blockIdx.x * 64, tid = threadIdx.x;
    const int* bst = (const int*)ws + BSTo;
    size_t tb = (size_t)b * 4097 * 64;
    if (tid < 64) {
        int j = j0 + tid;
        float dj = ws[Do + b * 4096 + j];
        float edj = expf(dj);
        int kb = bucket_of(-dj);
        int t = bst[b * NB + kb];
        float sa2  = ws[SA2o + b * 4097 + t];
        float sb2p = ws[SB2o + b * 4097 + t];
        float totA = ws[SB2o + b * 4097 + 4096];
        float den = 1.5f * ((totA - sb2p) + dj * (float)(4096 - t) - (float)t + edj * sa2);
        tarr[tid] = t; djs[tid] = dj; edjs[tid] = edj; invden[tid] = 1.0f / den;
    } else if (tid < 128) {
        int c = tid - 64;  tot1[c] = ws[T1o + tb + (size_t)4096 * 64 + c];
    } else if (tid < 192) {
        int c = tid - 128; tot3[c] = ws[T3o + tb + (size_t)4096 * 64 + c];
    } else {
        int c = tid - 192; bgs[c] = bg[c];
    }
    __syncthreads();
    {
        int c = tid & 63, jq = tid >> 6;
        for (int jj = jq; jj < 64; jj += 4) {
            size_t row = tb + (size_t)tarr[jj] * 64 + c;
            L1s[jj][c] = ws[T1o + row];
            L2s[jj][c] = ws[T2o + row];
            L3s[jj][c] = ws[T3o + row];
        }
    }
    __syncthreads();
    {
        int jl = tid & 63, cq = tid >> 6;
        float dj = djs[jl], edj = edjs[jl], inv = invden[jl];
        for (int c = cq; c < 64; c += 4) {
            float num = (tot3[c] - L3s[jl][c]) + dj * tot1[c]
                      - (1.0f + dj) * L1s[jl][c] + edj * L2s[jl][c];
            out[((size_t)(b * 64 + c)) * 4096 + j0 + jl] = num * inv + bgs[c];
        }
    }
}

extern "C" void kernel_launch(void* const* d_in, const int* in_sizes, int n_in,
                              void* d_out, int out_size, void* d_ws, size_t ws_size,
                              hipStream_t stream) {
    const float* x   = (const float*)d_in[0];
    const float* Wq  = (const float*)d_in[1];
    const float* bq  = (const float*)d_in[2];
    const float* Wk  = (const float*)d_in[3];
    const float* bk  = (const float*)d_in[4];
    const float* wcq = (const float*)d_in[5];
    const float* wck = (const float*)d_in[6];
    const float* Wv  = (const float*)d_in[7];
    const float* bv  = (const float*)d_in[8];
    const float* Wg  = (const float*)d_in[9];
    const float* bg  = (const float*)d_in[10];
    float* ws  = (float*)d_ws;
    float* out = (float*)d_out;

    k_prep<<<1, 256, 0, stream>>>(Wq, bq, Wk, bk, wcq, wck, Wv, bv, Wg, ws);
    k_proj<<<dim3(64, 4), 256, 0, stream>>>(x, ws);
    k_rank<<<4, 256, 0, stream>>>(ws);
    k_part<<<dim3(64, 4), 64, 0, stream>>>(ws);
    k_scanpart<<<1, 320, 0, stream>>>(ws);
    k_final<<<dim3(64, 4), 64, 0, stream>>>(ws);
    k_out<<<dim3(64, 4), 256, 0, stream>>>(ws, out, bg);
}

// Round 2
// 139.697 us; speedup vs baseline: 1.1060x; 1.1060x over previous
//
#include <hip/hip_runtime.h>
#include <math.h>

#define NPIX 4096
#define NB   4096

// ---- workspace layout (float offsets) ----
#define WQEo   0
#define WKEo   64
#define MISCo  128            // [0]=abias [1]=dbias
#define BVGo   192
#define WVGo   256            // 4096
#define Ao     4352           // B*4096
#define Do     (Ao+16384)
#define VGo    (Do+16384)     // B*4096*64
#define ASo    (VGo+1048576)  // sorted a, B*4096
#define PERMo  (ASo+16384)    // int, B*4096
#define BSTo   (PERMo+16384)  // int, B*NB bucket starts
#define Po     (BSTo+16384)   // chunk partials [b][64ch][3][64c] = 49152
#define SA2o   (Po+49152)     // B*4097 prefix of e^a over sorted pos
#define SB2o   (SA2o+16388)   // B*4097 prefix of a
#define To     (SB2o+16388)   // interleaved tables [b][4097][3][64] = 3146496
// end = To + 3146496 = 4363272 floats (~17.5 MB)

__device__ __forceinline__ int bucket_of(float v) {
    int k = (int)((v + 16.0f) * 128.0f);
    k = k < 0 ? 0 : k;
    k = k > (NB - 1) ? (NB - 1) : k;
    return k;
}

// K1: wq_eff = wcq@Wq, wk_eff = wck@Wk, abias/dbias, Wvg = Wg@Wv, bvg = Wg@bv
__global__ void k_prep(const float* __restrict__ Wq, const float* __restrict__ bq,
                       const float* __restrict__ Wk, const float* __restrict__ bk,
                       const float* __restrict__ wcq, const float* __restrict__ wck,
                       const float* __restrict__ Wv, const float* __restrict__ bv,
                       const float* __restrict__ Wg, float* __restrict__ ws) {
    int tid = threadIdx.x;
    if (tid < 64) {
        float s1 = 0.f, s2 = 0.f;
        for (int o = 0; o < 16; o++) { s1 += wcq[o] * Wq[o * 64 + tid]; s2 += wck[o] * Wk[o * 64 + tid]; }
        ws[WQEo + tid] = s1; ws[WKEo + tid] = s2;
        float s3 = 0.f;
        for (int m = 0; m < 64; m++) s3 += Wg[tid * 64 + m] * bv[m];
        ws[BVGo + tid] = s3;
    } else if (tid == 64) {
        float s = 0.f; for (int o = 0; o < 16; o++) s += wcq[o] * bq[o];
        ws[MISCo + 0] = s;
    } else if (tid == 65) {
        float s = 0.f; for (int o = 0; o < 16; o++) s += wck[o] * bk[o];
        ws[MISCo + 1] = s;
    }
    for (int idx = tid; idx < 4096; idx += 256) {
        int o = idx >> 6, c = idx & 63;
        float s = 0.f;
        for (int m = 0; m < 64; m++) s += Wg[o * 64 + m] * Wv[m * 64 + c];
        ws[WVGo + idx] = s;
    }
}

// K2: per-pixel a, d, and vg = Wvg@x + bvg   (x is [B][64][4096])
__global__ void k_proj(const float* __restrict__ x, float* __restrict__ ws) {
    __shared__ float xt[64][68];
    __shared__ float wt[64][68];   // wt[c][o] = Wvg[o][c]
    int b = blockIdx.y, n0 = blockIdx.x * 64, tid = threadIdx.x;
    const float* xb = x + (size_t)b * 64 * 4096;
    for (int idx = tid; idx < 4096; idx += 256) {
        int c = idx >> 6, nl = idx & 63;
        xt[c][nl] = xb[(size_t)c * 4096 + n0 + nl];
        wt[idx & 63][idx >> 6] = ws[WVGo + idx];
    }
    __syncthreads();
    if (tid < 64) {
        float s1 = ws[MISCo + 0], s2 = ws[MISCo + 1];
        for (int c = 0; c < 64; c++) {
            float xv = xt[c][tid];
            s1 += ws[WQEo + c] * xv;
            s2 += ws[WKEo + c] * xv;
        }
        ws[Ao + b * 4096 + n0 + tid] = s1;
        ws[Do + b * 4096 + n0 + tid] = s2;
    }
    int o = tid & 63, nl0 = (tid >> 6) * 16;
    float acc[16];
    float bo = ws[BVGo + o];
#pragma unroll
    for (int k = 0; k < 16; k++) acc[k] = bo;
    for (int c = 0; c < 64; c++) {
        float wv = wt[c][o];
        const float* xr = &xt[c][nl0];
#pragma unroll
        for (int k = 0; k < 16; k++) acc[k] += wv * xr[k];
    }
#pragma unroll
    for (int k = 0; k < 16; k++)
        ws[VGo + ((size_t)(b * 4096) + n0 + nl0 + k) * 64 + o] = acc[k];
}

// K3: per-batch bucket quasi-sort of a: hist -> scan -> scatter (rank by bucket)
__global__ void k_rank(float* __restrict__ ws) {
    __shared__ unsigned int hist[NB];
    __shared__ unsigned int cnt[NB];
    __shared__ unsigned int scanbuf[256];
    int b = blockIdx.x, tid = threadIdx.x;
    const float* Ab = ws + Ao + b * 4096;
    int* perm = (int*)ws + PERMo;
    int* bst  = (int*)ws + BSTo;
    for (int i = tid; i < NB; i += 256) { hist[i] = 0u; cnt[i] = 0u; }
    __syncthreads();
    for (int i = tid; i < 4096; i += 256) atomicAdd(&hist[bucket_of(Ab[i])], 1u);
    __syncthreads();
    unsigned int s = 0u;
    int base = tid * 16;
    for (int k = 0; k < 16; k++) s += hist[base + k];
    scanbuf[tid] = s;
    __syncthreads();
    for (int off = 1; off < 256; off <<= 1) {
        unsigned int v = scanbuf[tid];
        unsigned int u = (tid >= off) ? scanbuf[tid - off] : 0u;
        __syncthreads();
        scanbuf[tid] = v + u;
        __syncthreads();
    }
    unsigned int run = (tid > 0) ? scanbuf[tid - 1] : 0u;
    for (int k = 0; k < 16; k++) {
        unsigned int h = hist[base + k];
        hist[base + k] = run;
        bst[b * NB + base + k] = (int)run;
        run += h;
    }
    __syncthreads();
    for (int i = tid; i < 4096; i += 256) {
        float av = Ab[i];
        int kb = bucket_of(av);
        unsigned int r = hist[kb] + atomicAdd(&cnt[kb], 1u);
        ws[ASo + b * 4096 + r] = av;
        perm[b * 4096 + r] = i;
    }
}

// K4: chunk partials. block=(ch,b), 256 thr = 4 waves x 64 lanes(channel).
// wave w handles 16 sorted positions; combine in LDS -> P[b][ch][3][64].
__global__ void k_part(float* __restrict__ ws) {
    __shared__ float part[4][3][64];
    int b = blockIdx.y, ch = blockIdx.x;
    int tid = threadIdx.x, c = tid & 63, w = tid >> 6;
    const int* perm = (const int*)ws + PERMo;
    int r0 = ch * 64 + w * 16;
    float s1 = 0.f, s2 = 0.f, s3 = 0.f;
#pragma unroll 4
    for (int k = 0; k < 16; k++) {
        int r = r0 + k;
        int p = perm[b * 4096 + r];
        float av = ws[ASo + b * 4096 + r];
        float ea = expf(av);
        float wv = ws[VGo + ((size_t)(b * 4096) + p) * 64 + c];
        s1 += wv; s2 += wv * ea; s3 += wv * av;
    }
    part[w][0][c] = s1; part[w][1][c] = s2; part[w][2][c] = s3;
    __syncthreads();
    if (tid < 192) {
        int g = tid >> 6, cc = tid & 63;
        float s = part[0][g][cc] + part[1][g][cc] + part[2][g][cc] + part[3][g][cc];
        ws[Po + ((b * 64 + ch) * 3 + g) * 64 + cc] = s;
    }
}

// K5: per-batch block. Phase A: exclusive scan of chunk partials (in LDS).
//     Phase B: scalar prefix scans SA2/SB2 over 4096 sorted positions.
__global__ void k_scan(float* __restrict__ ws) {
    __shared__ float lds[12288];
    __shared__ float sc_ea[256], sc_a[256];
    int b = blockIdx.x, tid = threadIdx.x;
    for (int i = tid; i < 12288; i += 256) lds[i] = ws[Po + b * 12288 + i];
    __syncthreads();
    if (tid < 192) {
        float r = 0.f;
        for (int ch = 0; ch < 64; ch++) {
            float v = lds[ch * 192 + tid];
            lds[ch * 192 + tid] = r;
            r += v;
        }
    }
    __syncthreads();
    for (int i = tid; i < 12288; i += 256) ws[Po + b * 12288 + i] = lds[i];
    // Phase B
    float la[16], lea[16];
    int base = b * 4096 + tid * 16;
    float sea = 0.f, sa = 0.f;
#pragma unroll
    for (int k = 0; k < 16; k++) {
        float av = ws[ASo + base + k];
        la[k] = av; lea[k] = expf(av);
        sea += lea[k]; sa += la[k];
    }
    sc_ea[tid] = sea; sc_a[tid] = sa;
    __syncthreads();
    for (int off = 1; off < 256; off <<= 1) {
        float v1 = sc_ea[tid], v2 = sc_a[tid];
        float u1 = (tid >= off) ? sc_ea[tid - off] : 0.f;
        float u2 = (tid >= off) ? sc_a[tid - off] : 0.f;
        __syncthreads();
        sc_ea[tid] = v1 + u1; sc_a[tid] = v2 + u2;
        __syncthreads();
    }
    float rea = (tid > 0) ? sc_ea[tid - 1] : 0.f;
    float ra  = (tid > 0) ? sc_a[tid - 1] : 0.f;
#pragma unroll
    for (int k = 0; k < 16; k++) {
        ws[SA2o + b * 4097 + tid * 16 + k] = rea;
        ws[SB2o + b * 4097 + tid * 16 + k] = ra;
        rea += lea[k]; ra += la[k];
    }
    if (tid == 255) { ws[SA2o + b * 4097 + 4096] = rea; ws[SB2o + b * 4097 + 4096] = ra; }
}

// K6: write exclusive-prefix table rows T[b][t][3][64].
// block=(ch,b), 4 waves x 16 positions each; in-block 2-level prefix.
__global__ void k_final(float* __restrict__ ws) {
    __shared__ float part[4][3][64];
    int b = blockIdx.y, ch = blockIdx.x;
    int tid = threadIdx.x, c = tid & 63, w = tid >> 6;
    const int* perm = (const int*)ws + PERMo;
    int r0 = ch * 64 + w * 16;
    float s1 = 0.f, s2 = 0.f, s3 = 0.f;
    float avs[16], eas[16], wvs[16];
#pragma unroll 4
    for (int k = 0; k < 16; k++) {
        int r = r0 + k;
        int p = perm[b * 4096 + r];
        float av = ws[ASo + b * 4096 + r];
        float ea = expf(av);
        float wv = ws[VGo + ((size_t)(b * 4096) + p) * 64 + c];
        avs[k] = av; eas[k] = ea; wvs[k] = wv;
        s1 += wv; s2 += wv * ea; s3 += wv * av;
    }
    part[w][0][c] = s1; part[w][1][c] = s2; part[w][2][c] = s3;
    __syncthreads();
    int pbase = ((b * 64 + ch) * 3) * 64;
    float r1 = ws[Po + pbase + 0 * 64 + c];
    float r2 = ws[Po + pbase + 1 * 64 + c];
    float r3 = ws[Po + pbase + 2 * 64 + c];
    for (int w2 = 0; w2 < w; w2++) {
        r1 += part[w2][0][c]; r2 += part[w2][1][c]; r3 += part[w2][2][c];
    }
    size_t tb = (size_t)b * 4097 * 192;
#pragma unroll 4
    for (int k = 0; k < 16; k++) {
        size_t row = tb + (size_t)(r0 + k) * 192;
        ws[To + row + c]        = r1;
        ws[To + row + 64 + c]   = r2;
        ws[To + row + 128 + c]  = r3;
        r1 += wvs[k]; r2 += wvs[k] * eas[k]; r3 += wvs[k] * avs[k];
    }
    if (ch == 63 && w == 3) {
        size_t row = tb + (size_t)4096 * 192;
        ws[To + row + c] = r1; ws[To + row + 64 + c] = r2; ws[To + row + 128 + c] = r3;
    }
}

// K7: per j: t_j lookup, denom, gather interleaved table row -> LDS -> out
__global__ void k_out(float* __restrict__ ws, float* __restrict__ out,
                      const float* __restrict__ bg) {
    __shared__ float L[64][193];
    __shared__ float djs[64], edjs[64], invden[64];
    __shared__ int   tarr[64];
    __shared__ float tot1[64], tot3[64], bgs[64];
    int b = blockIdx.y, j0 = blockIdx.x * 64, tid = threadIdx.x;
    const int* bst = (const int*)ws + BSTo;
    size_t tb = (size_t)b * 4097 * 192;
    if (tid < 64) {
        int j = j0 + tid;
        float dj = ws[Do + b * 4096 + j];
        float edj = expf(dj);
        int kb = bucket_of(-dj);
        int t = bst[b * NB + kb];
        float sa2  = ws[SA2o + b * 4097 + t];
        float sb2p = ws[SB2o + b * 4097 + t];
        float totA = ws[SB2o + b * 4097 + 4096];
        float den = 1.5f * ((totA - sb2p) + dj * (float)(4096 - t) - (float)t + edj * sa2);
        tarr[tid] = t; djs[tid] = dj; edjs[tid] = edj; invden[tid] = 1.0f / den;
    } else if (tid < 128) {
        int c = tid - 64;
        tot1[c] = ws[To + tb + (size_t)4096 * 192 + c];
        bgs[c] = bg[c];
    } else if (tid < 192) {
        int c = tid - 128;
        tot3[c] = ws[To + tb + (size_t)4096 * 192 + 128 + c];
    }
    __syncthreads();
    {
        int c = tid & 63, jq = tid >> 6;
        for (int jj = jq; jj < 64; jj += 4) {
            size_t row = tb + (size_t)tarr[jj] * 192;
            L[jj][c]       = ws[To + row + c];
            L[jj][64 + c]  = ws[To + row + 64 + c];
            L[jj][128 + c] = ws[To + row + 128 + c];
        }
    }
    __syncthreads();
    {
        int jl = tid & 63, cq = tid >> 6;
        float dj = djs[jl], edj = edjs[jl], inv = invden[jl];
        for (int c = cq; c < 64; c += 4) {
            float num = (tot3[c] - L[jl][128 + c]) + dj * tot1[c]
                      - (1.0f + dj) * L[jl][c] + edj * L[jl][64 + c];
            out[((size_t)(b * 64 + c)) * 4096 + j0 + jl] = num * inv + bgs[c];
        }
    }
}

extern "C" void kernel_launch(void* const* d_in, const int* in_sizes, int n_in,
                              void* d_out, int out_size, void* d_ws, size_t ws_size,
                              hipStream_t stream) {
    const float* x   = (const float*)d_in[0];
    const float* Wq  = (const float*)d_in[1];
    const float* bq  = (const float*)d_in[2];
    const float* Wk  = (const float*)d_in[3];
    const float* bk  = (const float*)d_in[4];
    const float* wcq = (const float*)d_in[5];
    const float* wck = (const float*)d_in[6];
    const float* Wv  = (const float*)d_in[7];
    const float* bv  = (const float*)d_in[8];
    const float* Wg  = (const float*)d_in[9];
    const float* bg  = (const float*)d_in[10];
    float* ws  = (float*)d_ws;
    float* out = (float*)d_out;

    k_prep<<<1, 256, 0, stream>>>(Wq, bq, Wk, bk, wcq, wck, Wv, bv, Wg, ws);
    k_proj<<<dim3(64, 4), 256, 0, stream>>>(x, ws);
    k_rank<<<4, 256, 0, stream>>>(ws);
    k_part<<<dim3(64, 4), 256, 0, stream>>>(ws);
    k_scan<<<4, 256, 0, stream>>>(ws);
    k_final<<<dim3(64, 4), 256, 0, stream>>>(ws);
    k_out<<<dim3(64, 4), 256, 0, stream>>>(ws, out, bg);
}